// Round 10
// baseline (79498.431 us; speedup 1.0000x reference)
//
#include <hip/hip_runtime.h>
#include <math.h>

// CRvNN forward. N=64, S=130 (augmented), D=1024, 25 steps.
// Activations for the 3 big GEMMs stored as persistent f16 hi/lo planes
// (hi=f16(x), lo=f16((x-hi)*2048)); GEMM K-loop stages via
// __builtin_amdgcn_global_load_lds (16B, linear LDS dest, XOR-swizzled global
// source; ds_read applies the same XOR) -> zero conversion, no VGPR roundtrip.
// GEMM math: D = (Wh*Ah)/64 + (Wh*Al + Wl*Ah)/131072 (W planes carry x64).
// Workspace identical to round 9 (~180 MB + optional W^T tiers).

#define NB 64
#define SS 130
#define DD 1024
#define MM (NB*SS)
#define LSTR 132
#define CROWS 1664
#define RSC 2048.0f
#define IRS (1.0f/2048.0f)

typedef _Float16 f16x8 __attribute__((ext_vector_type(8)));
typedef _Float16 f16x4 __attribute__((ext_vector_type(4)));
typedef float f32x4 __attribute__((ext_vector_type(4)));

struct GemmSrcF { const float* a[5]; };
struct GemmSrcP { const _Float16* h[5]; const _Float16* l[5]; };
struct hl2 { _Float16 h, l; };

typedef const __attribute__((address_space(1))) void* gas_ptr;
typedef __attribute__((address_space(3))) void* las_ptr;

__device__ __forceinline__ void gload16(const void* g, void* l){
  __builtin_amdgcn_global_load_lds((gas_ptr)g, (las_ptr)l, 16, 0, 0);
}

__device__ __forceinline__ float bsum(float v){
  __shared__ float sh[4];
  __syncthreads();
  #pragma unroll
  for (int o=32;o;o>>=1) v += __shfl_down(v,o);
  if ((threadIdx.x & 63)==0) sh[threadIdx.x>>6] = v;
  __syncthreads();
  return sh[0]+sh[1]+sh[2]+sh[3];
}
__device__ __forceinline__ float bmaxr(float v){
  __shared__ float sh[4];
  __syncthreads();
  #pragma unroll
  for (int o=32;o;o>>=1) v = fmaxf(v,__shfl_down(v,o));
  if ((threadIdx.x & 63)==0) sh[threadIdx.x>>6] = v;
  __syncthreads();
  return fmaxf(fmaxf(sh[0],sh[1]),fmaxf(sh[2],sh[3]));
}
__device__ __forceinline__ float gelu_(float x){
  return 0.5f*x*(1.f+erff(x*0.70710678118654752f));
}
__device__ __forceinline__ hl2 enc(float x){
  hl2 r;
  r.h = (_Float16)x;
  r.l = (_Float16)((x - (float)r.h)*RSC);
  return r;
}

// ---------------- masks / augment ----------------
__global__ __launch_bounds__(256) void build_masks(
    const float* __restrict__ im, float* __restrict__ mk, float* __restrict__ sel,
    float* __restrict__ lastm, float* __restrict__ endm, float* __restrict__ ep,
    float* __restrict__ um, int* __restrict__ flag){
  int b = blockIdx.x, i = threadIdx.x;
  if (i < SS){
    float mye = (i<=1) ? 1.f : im[b*128 + (i-2)];
    float mne = (i==SS-1) ? 0.f : ((i==0) ? 1.f : im[b*128 + (i-1)]);
    float em  = mye - mne;
    float mns = (i==0) ? 0.f : mye;
    float lm;
    if (i < SS-1){
      int i1 = i+1;
      float mye1 = (i1<=1) ? 1.f : im[b*128 + (i1-2)];
      float mne1 = (i1==SS-1) ? 0.f : im[b*128 + (i1-1)];
      lm = mye1 - mne1;
    } else lm = 0.f;
    float sl = mns * mne * (1.f - lm);
    int idx = b*SS + i;
    mk[idx]=mye; sel[idx]=sl; lastm[idx]=lm; endm[idx]=em; ep[idx]=mye;
  } else if (i == SS) { um[b] = 1.f; }
  else if (i == SS+1 && b==0) { flag[0] = 0; }
}

__global__ __launch_bounds__(256) void build_seq(
    const float* __restrict__ seqin, const float* __restrict__ START,
    const float* __restrict__ END, const float* __restrict__ mk,
    const float* __restrict__ endm, float* __restrict__ out){
  int r = blockIdx.x; int b = r/SS, i = r%SS; int t = threadIdx.x;
  float em = endm[r], m = mk[r];
  #pragma unroll
  for (int q=0;q<4;q++){
    int j = t + q*256;
    float v;
    if (i==0) v = START[j];
    else if (i<=128) v = seqin[((size_t)b*128 + (i-1))*DD + j];
    else v = 0.f;
    v = em*END[j] + (1.f-em)*v;
    out[(size_t)r*DD + j] = v*m;
  }
}

// ---- weight transpose+convert (PRE tiers): W[K][N] f32 -> WT hi/lo [N][K] f16 ----
__global__ __launch_bounds__(256) void wtranspose(
    const float* __restrict__ W, _Float16* __restrict__ WTh, _Float16* __restrict__ WTl,
    int K, int N){
  __shared__ float Ts[32][33];
  int k0 = blockIdx.x*32, n0 = blockIdx.y*32;
  int t = threadIdx.x;
  int r = t>>3, c4 = (t&7)*4;
  float4 v = *(const float4*)(W + (size_t)(k0+r)*N + n0 + c4);
  Ts[r][c4]=v.x; Ts[r][c4+1]=v.y; Ts[r][c4+2]=v.z; Ts[r][c4+3]=v.w;
  __syncthreads();
  int n = t>>3, k4 = (t&7)*4;
  f16x4 h, lo;
  #pragma unroll
  for (int i=0;i<4;i++){
    hl2 e = enc(Ts[k4+i][n] * 64.f);
    h[i] = e.h; lo[i] = e.l;
  }
  *(f16x4*)(WTh + (size_t)(n0+n)*K + k0+k4) = h;
  *(f16x4*)(WTl + (size_t)(n0+n)*K + k0+k4) = lo;
}

// ---- MFMA GEMM: C[M,N] = planes-A[M,K] @ W[K,N], 128x128 tile, 4 waves ----
// Staging via global_load_lds: LDS linear [row][32] f16 (4 chunks of 8 per row);
// chunk slot q holds data octet q^(row&3) (source-address swizzle, rule #21).
// act: 0 f32 store, 1 gelu + planes store, 2 gelu + fused scorer partial
template<bool PREW>
__global__ __launch_bounds__(256,2) void gemm_mfma(
    GemmSrcP S, long lda,
    const _Float16* __restrict__ WTh, const _Float16* __restrict__ WTl,
    const float* __restrict__ Wf, int Nw,
    const float* __restrict__ bias,
    float* __restrict__ C, _Float16* __restrict__ Ch, _Float16* __restrict__ Cl,
    long ldc, int K, int act,
    const int* __restrict__ flag, float* __restrict__ spart, const float* __restrict__ Ws){
  if (flag[0]) return;
  __shared__ _Float16 Ah[128*32], Al[128*32];
  __shared__ _Float16 Wh[128*32], Wl[128*32];
  const int t = threadIdx.x;
  const int wave = t >> 6, lane = t & 63;
  const int wm = wave >> 1, wn = wave & 1;
  const int l15 = lane & 15, l4 = lane >> 4;
  // bijective XCD-chunked remap, m-fastest within chunk
  int lin = blockIdx.y * gridDim.x + blockIdx.x;
  int nwg = gridDim.x * gridDim.y;
  int q = nwg >> 3, r = nwg & 7;
  int xcd = lin & 7, pos = lin >> 3;
  int wg = (xcd < r) ? (xcd*(q+1) + pos) : (r*(q+1) + (xcd - r)*q + pos);
  int MT = gridDim.y;
  int mt = wg % MT, nt = wg / MT;
  const long mb = (long)mt * 128;
  const int  nb = nt * 128;
  f32x4 accH[4][4], accX[4][4];
  #pragma unroll
  for (int i=0;i<4;i++)
    #pragma unroll
    for (int j=0;j<4;j++){ accH[i][j] = (f32x4){0.f,0.f,0.f,0.f}; accX[i][j] = (f32x4){0.f,0.f,0.f,0.f}; }

  for (int kt=0; kt<K; kt+=32){
    // ---- A stage: global_load_lds, per-lane swizzled source ----
    #pragma unroll
    for (int p=0;p<2;p++){
      int f = t + 256*p;
      int m = f >> 2;
      int qs = f & 3;
      int qd = qs ^ (m & 3);
      int kg = kt + qd*8;
      const _Float16* sh = S.h[kg >> 10];
      const _Float16* sl = S.l[kg >> 10];
      size_t goff = (size_t)(mb + m)*lda + (kg & 1023);
      int lbase = (wave*64 + 256*p)*8;
      gload16(sh + goff, &Ah[lbase]);
      gload16(sl + goff, &Al[lbase]);
    }
    if constexpr (PREW){
      // ---- W stage: global_load_lds from preconverted [N][K] planes ----
      #pragma unroll
      for (int p=0;p<2;p++){
        int f = t + 256*p;
        int n = f >> 2;
        int qs = f & 3;
        int qd = qs ^ (n & 3);
        size_t goff = (size_t)(nb + n)*K + kt + qd*8;
        int lbase = (wave*64 + 256*p)*8;
        gload16(WTh + goff, &Wh[lbase]);
        gload16(WTl + goff, &Wl[lbase]);
      }
    } else {
      // ---- W stage: reg-staged transpose+split from f32 W[K][N] into same layout ----
      #pragma unroll
      for (int p=0;p<2;p++){
        int idx = t + 256*p;
        int n = idx >> 2;
        int qs = idx & 3;
        int qd = qs ^ (n & 3);
        const float* wsrc = Wf + (size_t)(kt + qd*8)*Nw + nb + n;
        f16x8 h8, l8;
        #pragma unroll
        for (int j=0;j<8;j++){
          hl2 e = enc(wsrc[(size_t)j*Nw] * 64.f);
          h8[j]=e.h; l8[j]=e.l;
        }
        *(f16x8*)&Wh[idx*8] = h8;
        *(f16x8*)&Wl[idx*8] = l8;
      }
    }
    __syncthreads();
    f16x8 wh[4], wl[4];
    #pragma unroll
    for (int i=0;i<4;i++){
      int rw = wn*64 + i*16 + l15;
      int off = rw*32 + (l4 ^ (rw&3))*8;
      wh[i] = *(const f16x8*)&Wh[off];
      wl[i] = *(const f16x8*)&Wl[off];
    }
    #pragma unroll
    for (int mi=0;mi<4;mi++){
      int ra = wm*64 + mi*16 + l15;
      int off = ra*32 + (l4 ^ (ra&3))*8;
      f16x8 ahv = *(const f16x8*)&Ah[off];
      f16x8 alv = *(const f16x8*)&Al[off];
      #pragma unroll
      for (int ni=0;ni<4;ni++){
        accH[mi][ni] = __builtin_amdgcn_mfma_f32_16x16x32_f16(wh[ni], ahv, accH[mi][ni], 0,0,0);
        accX[mi][ni] = __builtin_amdgcn_mfma_f32_16x16x32_f16(wh[ni], alv, accX[mi][ni], 0,0,0);
        accX[mi][ni] = __builtin_amdgcn_mfma_f32_16x16x32_f16(wl[ni], ahv, accX[mi][ni], 0,0,0);
      }
    }
    __syncthreads();
  }

  const float IH = 1.f/64.f, IX = 1.f/131072.f;
  if (act==2){
    #pragma unroll
    for (int mi=0;mi<4;mi++){
      float s = 0.f;
      #pragma unroll
      for (int ni=0;ni<4;ni++){
        int nbase = nb + wn*64 + ni*16 + 4*l4;
        #pragma unroll
        for (int rr=0;rr<4;rr++){
          float v = gelu_(accH[mi][ni][rr]*IH + accX[mi][ni][rr]*IX + bias[nbase+rr]);
          s = fmaf(v, Ws[nbase+rr], s);
        }
      }
      s += __shfl_xor(s, 16);
      s += __shfl_xor(s, 32);
      if (l4==0){
        long m = mb + wm*64 + mi*16 + l15;
        spart[m*16 + nt*2 + wn] = s;
      }
    }
    return;
  }
  #pragma unroll
  for (int mi=0;mi<4;mi++){
    long m = mb + wm*64 + mi*16 + l15;
    #pragma unroll
    for (int ni=0;ni<4;ni++){
      int nbase = nb + wn*64 + ni*16 + 4*l4;
      float v0 = accH[mi][ni][0]*IH + accX[mi][ni][0]*IX + bias[nbase+0];
      float v1 = accH[mi][ni][1]*IH + accX[mi][ni][1]*IX + bias[nbase+1];
      float v2 = accH[mi][ni][2]*IH + accX[mi][ni][2]*IX + bias[nbase+2];
      float v3 = accH[mi][ni][3]*IH + accX[mi][ni][3]*IX + bias[nbase+3];
      if (act==1){
        v0=gelu_(v0); v1=gelu_(v1); v2=gelu_(v2); v3=gelu_(v3);
        hl2 e0=enc(v0), e1=enc(v1), e2=enc(v2), e3=enc(v3);
        f16x4 h4; h4[0]=e0.h; h4[1]=e1.h; h4[2]=e2.h; h4[3]=e3.h;
        f16x4 l4v; l4v[0]=e0.l; l4v[1]=e1.l; l4v[2]=e2.l; l4v[3]=e3.l;
        *(f16x4*)(Ch + m*ldc + nbase) = h4;
        *(f16x4*)(Cl + m*ldc + nbase) = l4v;
      } else {
        float4 v; v.x=v0; v.y=v1; v.z=v2; v.w=v3;
        *(float4*)(C + m*ldc + nbase) = v;
      }
    }
  }
}

// ---- f32 GEMM (init only) ----
__global__ __launch_bounds__(256,2) void gemm_f32(
    GemmSrcF S, long lda, const float* __restrict__ B, const float* __restrict__ bias,
    float* __restrict__ C, long ldc, int N, int K, int act,
    const int* __restrict__ flag){
  if (flag[0]) return;
  __shared__ float Asm[16][132];
  __shared__ float Bsm[16][132];
  float acc[8][8];
  #pragma unroll
  for (int i=0;i<8;i++)
    #pragma unroll
    for (int j=0;j<8;j++) acc[i][j]=0.f;
  const int t = threadIdx.x;
  const int tx = t & 15, ty = t >> 4;
  const long mb = (long)blockIdx.y * 128;
  const int  nb = blockIdx.x * 128;
  for (int kt=0; kt<K; kt+=16){
    #pragma unroll
    for (int ii=0; ii<2; ii++){
      int f  = t + 256*ii;
      int m  = f >> 2;
      int k4 = (f & 3) * 4;
      int kg = kt + k4;
      const float* src = S.a[kg >> 10];
      float4 v = *(const float4*)(src + (mb + m)*lda + (kg & 1023));
      Asm[k4+0][m]=v.x; Asm[k4+1][m]=v.y; Asm[k4+2][m]=v.z; Asm[k4+3][m]=v.w;
    }
    #pragma unroll
    for (int ii=0; ii<2; ii++){
      int f  = t + 256*ii;
      int kk = f >> 5;
      int c4 = (f & 31)*4;
      *(float4*)&Bsm[kk][c4] = *(const float4*)(B + (long)(kt+kk)*N + nb + c4);
    }
    __syncthreads();
    #pragma unroll
    for (int kk=0;kk<16;kk++){
      float av[8], bv[8];
      *(float4*)&av[0] = *(const float4*)&Asm[kk][ty*4];
      *(float4*)&av[4] = *(const float4*)&Asm[kk][64+ty*4];
      *(float4*)&bv[0] = *(const float4*)&Bsm[kk][tx*4];
      *(float4*)&bv[4] = *(const float4*)&Bsm[kk][64+tx*4];
      #pragma unroll
      for (int r=0;r<8;r++)
        #pragma unroll
        for (int c=0;c<8;c++) acc[r][c] = fmaf(av[r],bv[c],acc[r][c]);
    }
    __syncthreads();
  }
  #pragma unroll
  for (int rh=0;rh<2;rh++)
  #pragma unroll
  for (int rr=0;rr<4;rr++){
    long row = mb + rh*64 + ty*4 + rr;
    #pragma unroll
    for (int ch=0;ch<2;ch++){
      int col = nb + ch*64 + tx*4;
      float4 v;
      v.x = acc[rh*4+rr][ch*4+0] + bias[col+0];
      v.y = acc[rh*4+rr][ch*4+1] + bias[col+1];
      v.z = acc[rh*4+rr][ch*4+2] + bias[col+2];
      v.w = acc[rh*4+rr][ch*4+3] + bias[col+3];
      *(float4*)(C + row*ldc + col) = v;
    }
  }
}

// ---- batched neighbor GEMM: Y[b] = P[b](130x130,pad132) @ X[b](130x1024) ----
__global__ __launch_bounds__(256,2) void bgemm(
    const float* __restrict__ P,
    const _Float16* __restrict__ Xh, const _Float16* __restrict__ Xl,
    _Float16* __restrict__ Yh, _Float16* __restrict__ Yl,
    const int* __restrict__ flag){
  if (flag[0]) return;
  __shared__ float Ps[64][17];
  __shared__ float Xs[16][132];
  const int t = threadIdx.x;
  const int nt = blockIdx.x, mt = blockIdx.y, b = blockIdx.z;
  const int i0 = mt*64;
  const float* Pb = P + (size_t)b*SS*LSTR;
  const _Float16* Xhb = Xh + (size_t)b*SS*DD + nt*128;
  const _Float16* Xlb = Xl + (size_t)b*SS*DD + nt*128;
  _Float16* Yhb = Yh + (size_t)b*SS*DD + nt*128;
  _Float16* Ylb = Yl + (size_t)b*SS*DD + nt*128;
  const int tx = t & 7, ty = t >> 3;
  float acc[2][16];
  #pragma unroll
  for (int r=0;r<2;r++)
    #pragma unroll
    for (int c=0;c<16;c++) acc[r][c]=0.f;
  for (int j0=0;j0<SS;j0+=16){
    { int r = t>>2, c0 = (t&3)*4;
      float4 v = make_float4(0.f,0.f,0.f,0.f);
      if (i0 + r < SS && j0 + c0 < LSTR) v = *(const float4*)(Pb + (size_t)(i0+r)*LSTR + j0 + c0);
      Ps[r][c0]=v.x; Ps[r][c0+1]=v.y; Ps[r][c0+2]=v.z; Ps[r][c0+3]=v.w;
    }
    #pragma unroll
    for (int ii=0;ii<2;ii++){
      int f = t + 256*ii;
      int jj = f>>5, c4 = (f&31)*4;
      float x0=0.f,x1=0.f,x2=0.f,x3=0.f;
      if (j0 + jj < SS){
        f16x4 xh = *(const f16x4*)(Xhb + (size_t)(j0+jj)*DD + c4);
        f16x4 xl = *(const f16x4*)(Xlb + (size_t)(j0+jj)*DD + c4);
        x0 = (float)xh[0] + (float)xl[0]*IRS;
        x1 = (float)xh[1] + (float)xl[1]*IRS;
        x2 = (float)xh[2] + (float)xl[2]*IRS;
        x3 = (float)xh[3] + (float)xl[3]*IRS;
      }
      Xs[jj][c4]=x0; Xs[jj][c4+1]=x1; Xs[jj][c4+2]=x2; Xs[jj][c4+3]=x3;
    }
    __syncthreads();
    #pragma unroll
    for (int jj=0;jj<16;jj++){
      float p0 = Ps[2*ty][jj], p1 = Ps[2*ty+1][jj];
      #pragma unroll
      for (int q=0;q<4;q++){
        float4 xv = *(const float4*)&Xs[jj][tx*4 + 32*q];
        acc[0][q*4+0] = fmaf(p0,xv.x,acc[0][q*4+0]);
        acc[0][q*4+1] = fmaf(p0,xv.y,acc[0][q*4+1]);
        acc[0][q*4+2] = fmaf(p0,xv.z,acc[0][q*4+2]);
        acc[0][q*4+3] = fmaf(p0,xv.w,acc[0][q*4+3]);
        acc[1][q*4+0] = fmaf(p1,xv.x,acc[1][q*4+0]);
        acc[1][q*4+1] = fmaf(p1,xv.y,acc[1][q*4+1]);
        acc[1][q*4+2] = fmaf(p1,xv.z,acc[1][q*4+2]);
        acc[1][q*4+3] = fmaf(p1,xv.w,acc[1][q*4+3]);
      }
    }
    __syncthreads();
  }
  #pragma unroll
  for (int rr=0;rr<2;rr++){
    int row = i0 + 2*ty + rr;
    if (row < SS){
      #pragma unroll
      for (int q=0;q<4;q++){
        hl2 e0 = enc(acc[rr][q*4+0]);
        hl2 e1 = enc(acc[rr][q*4+1]);
        hl2 e2 = enc(acc[rr][q*4+2]);
        hl2 e3 = enc(acc[rr][q*4+3]);
        f16x4 h4; h4[0]=e0.h; h4[1]=e1.h; h4[2]=e2.h; h4[3]=e3.h;
        f16x4 l4v; l4v[0]=e0.l; l4v[1]=e1.l; l4v[2]=e2.l; l4v[3]=e3.l;
        *(f16x4*)(Yhb + (size_t)row*DD + tx*4 + 32*q) = h4;
        *(f16x4*)(Ylb + (size_t)row*DD + tx*4 + 32*q) = l4v;
      }
    }
  }
}

// ---------------- neighbor probabilities: wave-per-row prefix/suffix scan ----------------
__global__ __launch_bounds__(256) void neighbor_kernel(
    const float* __restrict__ ep, const float* __restrict__ mk,
    float* __restrict__ L, float* __restrict__ R, const int* __restrict__ flag){
  if (flag[0]) return;
  int wave = threadIdx.x >> 6, lane = threadIdx.x & 63;
  int idx = blockIdx.x*4 + wave;
  if (idx >= MM) return;
  int b = idx / SS, i = idx % SS;
  const float* p = ep + b*SS;
  const float* m = mk + b*SS;
  float mR[3], mL[3], mv[3];
  #pragma unroll
  for (int c=0;c<3;c++){
    int j = lane + 64*c;
    float pj = (j<SS)? p[j] : 0.f;
    float mj = (j<SS)? m[j] : 0.f;
    mv[c] = mj;
    float x = pj*mj;
    mR[c] = (j>i)? x : 0.f;
    mL[c] = (j<i)? x : 0.f;
  }
  float csR[3]; float run = 0.f;
  #pragma unroll
  for (int c=0;c<3;c++){
    float s = mR[c];
    #pragma unroll
    for (int o=1;o<64;o<<=1){ float v = __shfl_up(s,o); if (lane>=o) s += v; }
    csR[c] = s + run;
    run += __shfl(s,63);
  }
  float csL[3]; run = 0.f;
  #pragma unroll
  for (int cc=0;cc<3;cc++){
    int c = 2-cc;
    float s = mL[c];
    #pragma unroll
    for (int o=1;o<64;o<<=1){ float v = __shfl_down(s,o); if (lane < 64-o) s += v; }
    csL[c] = s + run;
    run += __shfl(s,0);
  }
  float* Lr = L + (size_t)idx*LSTR;
  float* Rr = R + (size_t)idx*LSTR;
  #pragma unroll
  for (int c=0;c<3;c++){
    int j = lane + 64*c;
    if (j < LSTR){
      float rv = 0.f, lv = 0.f;
      if (j < SS){
        rv = ((csR[c]>1.f) ? fmaxf(1.f-(csR[c]-mR[c]),0.f) : mR[c]) * mv[c];
        lv = ((csL[c]>1.f) ? fmaxf(1.f-(csL[c]-mL[c]),0.f) : mL[c]) * mv[c];
      }
      Rr[j] = rv; Lr[j] = lv;
    }
  }
}

// ---------------- LN after init: f32 in -> sq planes out ----------------
__global__ __launch_bounds__(256) void ln1_kernel(
    const float* __restrict__ xin, const float* __restrict__ g, const float* __restrict__ bb,
    const float* __restrict__ mk, _Float16* __restrict__ sqh, _Float16* __restrict__ sql){
  int r = blockIdx.x, t = threadIdx.x;
  const float* xr = xin + (size_t)r*DD;
  float x[4]; float s=0.f;
  #pragma unroll
  for (int q=0;q<4;q++){ x[q]=xr[t+256*q]; s+=x[q]; }
  float mean = bsum(s)*(1.f/DD);
  float vs=0.f;
  #pragma unroll
  for (int q=0;q<4;q++){ float d=x[q]-mean; vs+=d*d; }
  float var = bsum(vs)*(1.f/DD);
  float inv = 1.f/sqrtf(var+1e-5f);
  float m = mk[r];
  #pragma unroll
  for (int q=0;q<4;q++){
    int j=t+256*q;
    float v = ((x[q]-mean)*inv*g[j]+bb[j])*m;
    hl2 e = enc(v);
    sqh[(size_t)r*DD+j] = e.h; sql[(size_t)r*DD+j] = e.l;
  }
}

// ---------------- scorer finalize / max / tp ----------------
__global__ void scorer_final(const float* __restrict__ spart, const float* __restrict__ bs,
                             float* __restrict__ sc, const int* __restrict__ flag){
  if (flag[0]) return;
  int r = blockIdx.x*blockDim.x + threadIdx.x;
  if (r >= MM) return;
  float s = bs[0];
  #pragma unroll
  for (int k=0;k<16;k++) s += spart[(size_t)r*16+k];
  sc[r] = s;
}
__global__ __launch_bounds__(256) void max1(const float* __restrict__ sc, float* __restrict__ part,
                                            const int* __restrict__ flag){
  if (flag[0]) return;
  int idx = blockIdx.x*256 + threadIdx.x;
  float v = -1e30f;
  for (int i = idx; i < MM; i += 64*256) v = fmaxf(v, sc[i]);
  v = bmaxr(v);
  if (threadIdx.x==0) part[blockIdx.x] = v;
}
__global__ __launch_bounds__(64) void max2(const float* __restrict__ part, float* __restrict__ gm,
                                           const int* __restrict__ flag){
  if (flag[0]) return;
  float v = part[threadIdx.x];
  #pragma unroll
  for (int o=32;o;o>>=1) v = fmaxf(v, __shfl_down(v,o));
  if (threadIdx.x==0) gm[0] = fmaxf(v, 0.f);
}
__global__ void tp_kernel(const float* __restrict__ sc, const float* __restrict__ sel,
                          const float* __restrict__ um, const float* __restrict__ gm,
                          float* __restrict__ tp, const int* __restrict__ flag){
  if (flag[0]) return;
  int idx = blockIdx.x*blockDim.x + threadIdx.x;
  if (idx>=MM) return;
  int b = idx / SS;
  float g = gm[0];
  float et = expf(sc[idx]-g)*sel[idx];
  float en = expf(-g);
  tp[idx] = et/(et+en+2e-8f)*um[b];
}

// ---- gates + LN + blend, planes in/out, row-chunked ----
__global__ __launch_bounds__(256) void update_kernel(
    const float* __restrict__ cont,
    const _Float16* __restrict__ l1h, const _Float16* __restrict__ l1l,
    _Float16* __restrict__ sqh, _Float16* __restrict__ sql,
    const float* __restrict__ tp, const float* __restrict__ g, const float* __restrict__ bb,
    const int* __restrict__ flag, long row0){
  if (flag[0]) return;
  long r = row0 + blockIdx.x; int t = threadIdx.x;
  const float* cr = cont + (size_t)blockIdx.x*4096;
  const _Float16* lh = l1h + (size_t)r*DD;
  const _Float16* ll = l1l + (size_t)r*DD;
  _Float16* sh = sqh + (size_t)r*DD;
  _Float16* sl = sql + (size_t)r*DD;
  float x[4], sv[4];
  float s=0.f;
  #pragma unroll
  for (int q=0;q<4;q++){
    int j = t+q*256;
    float c0=cr[j], c1=cr[DD+j], c2=cr[2*DD+j], c3=cr[3*DD+j];
    float g0=1.f/(1.f+expf(-c0));
    float g1=1.f/(1.f+expf(-c1));
    float g2=1.f/(1.f+expf(-c2));
    float lv = (float)lh[j] + (float)ll[j]*IRS;
    float sqv = (float)sh[j] + (float)sl[j]*IRS;
    sv[q]=sqv;
    x[q] = g0*lv + g1*sqv + g2*c3;
    s += x[q];
  }
  float mean = bsum(s)*(1.f/DD);
  float vs=0.f;
  #pragma unroll
  for (int q=0;q<4;q++){ float d=x[q]-mean; vs+=d*d; }
  float var = bsum(vs)*(1.f/DD);
  float inv = 1.f/sqrtf(var+1e-5f);
  float tpv = tp[r];
  #pragma unroll
  for (int q=0;q<4;q++){
    int j=t+q*256;
    float comp = (x[q]-mean)*inv*g[j]+bb[j];
    float out = tpv*comp + (1.f-tpv)*sv[q];
    hl2 e = enc(out);
    sh[j]=e.h; sl[j]=e.l;
  }
}

// ---------------- ep update: wave-per-row dot ----------------
__global__ __launch_bounds__(256) void ep_update(
    float* __restrict__ ep, const float* __restrict__ R,
    const float* __restrict__ tp, const int* __restrict__ flag){
  if (flag[0]) return;
  int wave = threadIdx.x >> 6, lane = threadIdx.x & 63;
  int idx = blockIdx.x*4 + wave;
  if (idx >= MM) return;
  int b = idx / SS;
  const float* Rr = R + (size_t)idx*LSTR;
  const float* tb = tp + b*SS;
  float d = 0.f;
  #pragma unroll
  for (int c=0;c<3;c++){
    int j = lane + 64*c;
    if (j < SS) d = fmaf(Rr[j], tb[j], d);
  }
  #pragma unroll
  for (int o=32;o;o>>=1) d += __shfl_xor(d,o);
  if (lane==0) ep[idx] *= (1.f - d);
}

__global__ __launch_bounds__(256) void active_um(const float* __restrict__ ep,
                                                 const float* __restrict__ sel,
                                                 float* __restrict__ um,
                                                 const int* __restrict__ flag){
  if (flag[0]) return;
  int b = blockIdx.x, t = threadIdx.x;
  float s = (t<SS) ? ep[b*SS+t]*sel[b*SS+t] : 0.f;
  s = bsum(s);
  if (t==0) um[b] *= (s >= 0.1f) ? 1.f : 0.f;
}
__global__ __launch_bounds__(64) void done_kernel(const float* __restrict__ um, int* __restrict__ flag){
  float v = um[threadIdx.x];
  unsigned long long b = __ballot(v > 0.f);
  if (threadIdx.x==0) flag[0] = (b==0ULL) ? 1 : 0;
}

// ---------------- outputs (reconstruct sq from planes) ----------------
__global__ __launch_bounds__(256) void output_kernel(
    const _Float16* __restrict__ sqh, const _Float16* __restrict__ sql,
    const float* __restrict__ mk, float* __restrict__ out){
  int r = blockIdx.x; int b = r/SS, i = r%SS;
  if (i<1 || i>128) return;
  float m = mk[r]; int t=threadIdx.x;
  #pragma unroll
  for (int q=0;q<4;q++){
    int j = t+q*256;
    float v = (float)sqh[(size_t)r*DD+j] + (float)sql[(size_t)r*DD+j]*IRS;
    out[((size_t)b*128 + (i-1))*DD + j] = v*m;
  }
}
__global__ __launch_bounds__(256) void gstate_kernel(
    const _Float16* __restrict__ sqh, const _Float16* __restrict__ sql,
    const float* __restrict__ mk, const float* __restrict__ lastm,
    float* __restrict__ outg){
  int b = blockIdx.x; int t=threadIdx.x;
  #pragma unroll
  for (int q=0;q<4;q++){
    int j = t+q*256;
    float acc=0.f;
    for (int i=0;i<SS;i++){
      float w = lastm[b*SS+i]*mk[b*SS+i];
      size_t o = ((size_t)(b*SS+i))*DD + j;
      float v = (float)sqh[o] + (float)sql[o]*IRS;
      acc = fmaf(w, v, acc);
    }
    outg[(size_t)b*DD + j] = acc;
  }
}

extern "C" void kernel_launch(void* const* d_in, const int* in_sizes, int n_in,
                              void* d_out, int out_size, void* d_ws, size_t ws_size,
                              hipStream_t stream) {
  const float* sequence   = (const float*)d_in[0];
  const float* input_mask = (const float*)d_in[1];
  const float* START      = (const float*)d_in[2];
  const float* END        = (const float*)d_in[3];
  const float* W_conv     = (const float*)d_in[4];
  const float* b_conv     = (const float*)d_in[5];
  const float* W_scorer   = (const float*)d_in[6];
  const float* b_scorer   = (const float*)d_in[7];
  const float* W_init     = (const float*)d_in[8];
  const float* b_init     = (const float*)d_in[9];
  const float* W_cell1    = (const float*)d_in[10];
  const float* b_cell1    = (const float*)d_in[11];
  const float* W_cell2    = (const float*)d_in[12];
  const float* b_cell2    = (const float*)d_in[13];
  const float* ln1g       = (const float*)d_in[14];
  const float* ln1b       = (const float*)d_in[15];
  const float* ln2g       = (const float*)d_in[16];
  const float* ln2b       = (const float*)d_in[17];

  float* ws = (float*)d_ws;
  const size_t U = (size_t)MM*DD;
  _Float16* sq_h = (_Float16*)(ws);        _Float16* sq_l = sq_h + U;
  _Float16* l1_h = (_Float16*)(ws + U);    _Float16* l1_l = l1_h + U;
  _Float16* r1_h = (_Float16*)(ws + 2*U);  _Float16* r1_l = r1_h + U;
  _Float16* l2_h = (_Float16*)(ws + 3*U);  _Float16* l2_l = l2_h + U;  // also hid planes (chunk)
  _Float16* r2_h = (_Float16*)(ws + 4*U);  _Float16* r2_l = r2_h + U;
  float* contb = ws + 4*U;                 // cont f32 chunk aliases r2 region
  float* seqtmp  = ws + U;                 // init scratch (l1 region as f32)
  float* inittmp = ws + 2*U;               // init scratch (r1 region as f32)
  float* Lm   = ws + 5*U;
  float* Rm   = Lm + (size_t)NB*SS*LSTR;
  float* maskv= Rm + (size_t)NB*SS*LSTR;
  float* sel  = maskv + MM;
  float* lastm= sel + MM;
  float* endm = lastm + MM;
  float* ep   = endm + MM;
  float* scb  = ep + MM;
  float* tpb  = scb + MM;
  float* spart= tpb + MM;          // MM*16
  float* umb  = spart + (size_t)MM*16;
  float* part = umb + NB;
  float* gmx  = part + 64;
  int*   flag = (int*)(gmx + 4);
  size_t used_floats = (size_t)((float*)(flag+4) - ws);
  used_floats = (used_floats + 7) & ~(size_t)7;
  const size_t SC = (size_t)1024*5120, S1 = (size_t)4096*2048, S2 = (size_t)4096*4096;
  _Float16* WT2_h = (_Float16*)(ws + used_floats);
  _Float16* WT2_l = WT2_h + S2;
  _Float16* WT1_h = WT2_l + S2;
  _Float16* WT1_l = WT1_h + S1;
  _Float16* WTc_h = WT1_l + S1;
  _Float16* WTc_l = WTc_h + SC;
  const bool pre2 = ws_size >= (size_t)((char*)(WT2_l + S2) - (char*)d_ws);
  const bool pre1 = ws_size >= (size_t)((char*)(WT1_l + S1) - (char*)d_ws);
  const bool prec = ws_size >= (size_t)((char*)(WTc_l + SC) - (char*)d_ws);

  build_masks<<<NB,256,0,stream>>>(input_mask, maskv, sel, lastm, endm, ep, umb, flag);
  build_seq<<<MM,256,0,stream>>>(sequence, START, END, maskv, endm, seqtmp);
  GemmSrcF si; si.a[0]=seqtmp; si.a[1]=seqtmp; si.a[2]=seqtmp; si.a[3]=seqtmp; si.a[4]=seqtmp;
  gemm_f32<<<dim3(8,65),256,0,stream>>>(si, DD, W_init, b_init, inittmp, DD, DD, DD, 0, flag);
  ln1_kernel<<<MM,256,0,stream>>>(inittmp, ln1g, ln1b, maskv, sq_h, sq_l);

  if (pre2) wtranspose<<<dim3(128,128),256,0,stream>>>(W_cell2, WT2_h, WT2_l, 4096, 4096);
  if (pre1) wtranspose<<<dim3(64,128),256,0,stream>>>(W_cell1, WT1_h, WT1_l, 2048, 4096);
  if (prec) wtranspose<<<dim3(160,32),256,0,stream>>>(W_conv,  WTc_h, WTc_l, 5120, 1024);

  const int NBLK = (MM + 3) / 4;
  for (int it=0; it<25; ++it){
    neighbor_kernel<<<NBLK,256,0,stream>>>(ep, maskv, Lm, Rm, flag);
    bgemm<<<dim3(8,3,NB),256,0,stream>>>(Lm, sq_h, sq_l, l1_h, l1_l, flag);
    bgemm<<<dim3(8,3,NB),256,0,stream>>>(Rm, sq_h, sq_l, r1_h, r1_l, flag);
    bgemm<<<dim3(8,3,NB),256,0,stream>>>(Lm, l1_h, l1_l, l2_h, l2_l, flag);
    bgemm<<<dim3(8,3,NB),256,0,stream>>>(Rm, r1_h, r1_l, r2_h, r2_l, flag);
    GemmSrcP s5;
    s5.h[0]=l2_h; s5.h[1]=l1_h; s5.h[2]=sq_h; s5.h[3]=r1_h; s5.h[4]=r2_h;
    s5.l[0]=l2_l; s5.l[1]=l1_l; s5.l[2]=sq_l; s5.l[3]=r1_l; s5.l[4]=r2_l;
    if (prec)
      gemm_mfma<true ><<<dim3(8,65),256,0,stream>>>(s5, DD, WTc_h, WTc_l, nullptr, 0, b_conv, nullptr, nullptr, nullptr, 0, 5120, 2, flag, spart, W_scorer);
    else
      gemm_mfma<false><<<dim3(8,65),256,0,stream>>>(s5, DD, nullptr, nullptr, W_conv, 1024, b_conv, nullptr, nullptr, nullptr, 0, 5120, 2, flag, spart, W_scorer);
    scorer_final<<<(MM+255)/256,256,0,stream>>>(spart, b_scorer, scb, flag);
    max1<<<64,256,0,stream>>>(scb, part, flag);
    max2<<<1,64,0,stream>>>(part, gmx, flag);
    tp_kernel<<<(MM+255)/256,256,0,stream>>>(scb, sel, umb, gmx, tpb, flag);
    for (int c=0;c<5;c++){
      long row0 = (long)c*CROWS;
      GemmSrcP s2;
      s2.h[0]=l1_h+row0*DD; s2.h[1]=sq_h+row0*DD; s2.h[2]=s2.h[1]; s2.h[3]=s2.h[1]; s2.h[4]=s2.h[1];
      s2.l[0]=l1_l+row0*DD; s2.l[1]=sq_l+row0*DD; s2.l[2]=s2.l[1]; s2.l[3]=s2.l[1]; s2.l[4]=s2.l[1];
      GemmSrcP s3;
      s3.h[0]=l2_h; s3.h[1]=l2_h+DD; s3.h[2]=l2_h+2*DD; s3.h[3]=l2_h+3*DD; s3.h[4]=l2_h;
      s3.l[0]=l2_l; s3.l[1]=l2_l+DD; s3.l[2]=l2_l+2*DD; s3.l[3]=l2_l+3*DD; s3.l[4]=l2_l;
      if (pre1)
        gemm_mfma<true ><<<dim3(32,13),256,0,stream>>>(s2, DD,   WT1_h, WT1_l, nullptr, 0, b_cell1, nullptr, l2_h, l2_l, 4096, 2048, 1, flag, nullptr, nullptr);
      else
        gemm_mfma<false><<<dim3(32,13),256,0,stream>>>(s2, DD,   nullptr, nullptr, W_cell1, 4096, b_cell1, nullptr, l2_h, l2_l, 4096, 2048, 1, flag, nullptr, nullptr);
      if (pre2)
        gemm_mfma<true ><<<dim3(32,13),256,0,stream>>>(s3, 4096, WT2_h, WT2_l, nullptr, 0, b_cell2, contb, nullptr, nullptr, 4096, 4096, 0, flag, nullptr, nullptr);
      else
        gemm_mfma<false><<<dim3(32,13),256,0,stream>>>(s3, 4096, nullptr, nullptr, W_cell2, 4096, b_cell2, contb, nullptr, nullptr, 4096, 4096, 0, flag, nullptr, nullptr);
      update_kernel<<<CROWS,256,0,stream>>>(contb, l1_h, l1_l, sq_h, sq_l, tpb, ln2g, ln2b, flag, row0);
    }
    ep_update<<<NBLK,256,0,stream>>>(ep, Rm, tpb, flag);
    active_um<<<NB,256,0,stream>>>(ep, sel, umb, flag);
    done_kernel<<<1,64,0,stream>>>(umb, flag);
  }

  float* out = (float*)d_out;
  output_kernel<<<MM,256,0,stream>>>(sq_h, sq_l, maskv, out);
  gstate_kernel<<<NB,256,0,stream>>>(sq_h, sq_l, maskv, lastm, out + (size_t)NB*128*DD);
}

// Round 11
// 61902.869 us; speedup vs baseline: 1.2842x; 1.2842x over previous
//
#include <hip/hip_runtime.h>
#include <math.h>

// CRvNN forward. N=64, S=130 (augmented), D=1024, 25 steps.
// Activations for the 3 big GEMMs stored as persistent f16 hi/lo planes.
// A staged via __builtin_amdgcn_global_load_lds (16B, linear LDS dest,
// sw(r)=(r+(r>>2))&3 XOR chunk swizzle applied on the global source and on
// ds_read). W: PRE tier -> gload_lds same way; else coalesced reg-staged
// transpose+split from f32 W[K][N] (round-9-style, lane-consecutive n).
// GEMM math: D = (Wh*Ah)/64 + (Wh*Al + Wl*Ah)/131072 (W planes carry x64).

#define NB 64
#define SS 130
#define DD 1024
#define MM (NB*SS)
#define LSTR 132
#define CROWS 1664
#define RSC 2048.0f
#define IRS (1.0f/2048.0f)

typedef _Float16 f16x8 __attribute__((ext_vector_type(8)));
typedef _Float16 f16x4 __attribute__((ext_vector_type(4)));
typedef _Float16 f16x2 __attribute__((ext_vector_type(2)));
typedef float f32x4 __attribute__((ext_vector_type(4)));

struct GemmSrcF { const float* a[5]; };
struct GemmSrcP { const _Float16* h[5]; const _Float16* l[5]; };
struct hl2 { _Float16 h, l; };

typedef const __attribute__((address_space(1))) void* gas_ptr;
typedef __attribute__((address_space(3))) void* las_ptr;

__device__ __forceinline__ void gload16(const void* g, void* l){
  __builtin_amdgcn_global_load_lds((gas_ptr)g, (las_ptr)l, 16, 0, 0);
}
__device__ __forceinline__ int sw4(int r){ return (r + (r>>2)) & 3; }

__device__ __forceinline__ float bsum(float v){
  __shared__ float sh[4];
  __syncthreads();
  #pragma unroll
  for (int o=32;o;o>>=1) v += __shfl_down(v,o);
  if ((threadIdx.x & 63)==0) sh[threadIdx.x>>6] = v;
  __syncthreads();
  return sh[0]+sh[1]+sh[2]+sh[3];
}
__device__ __forceinline__ float bmaxr(float v){
  __shared__ float sh[4];
  __syncthreads();
  #pragma unroll
  for (int o=32;o;o>>=1) v = fmaxf(v,__shfl_down(v,o));
  if ((threadIdx.x & 63)==0) sh[threadIdx.x>>6] = v;
  __syncthreads();
  return fmaxf(fmaxf(sh[0],sh[1]),fmaxf(sh[2],sh[3]));
}
__device__ __forceinline__ float gelu_(float x){
  return 0.5f*x*(1.f+erff(x*0.70710678118654752f));
}
__device__ __forceinline__ hl2 enc(float x){
  hl2 r;
  r.h = (_Float16)x;
  r.l = (_Float16)((x - (float)r.h)*RSC);
  return r;
}

// ---------------- masks / augment ----------------
__global__ __launch_bounds__(256) void build_masks(
    const float* __restrict__ im, float* __restrict__ mk, float* __restrict__ sel,
    float* __restrict__ lastm, float* __restrict__ endm, float* __restrict__ ep,
    float* __restrict__ um, int* __restrict__ flag){
  int b = blockIdx.x, i = threadIdx.x;
  if (i < SS){
    float mye = (i<=1) ? 1.f : im[b*128 + (i-2)];
    float mne = (i==SS-1) ? 0.f : ((i==0) ? 1.f : im[b*128 + (i-1)]);
    float em  = mye - mne;
    float mns = (i==0) ? 0.f : mye;
    float lm;
    if (i < SS-1){
      int i1 = i+1;
      float mye1 = (i1<=1) ? 1.f : im[b*128 + (i1-2)];
      float mne1 = (i1==SS-1) ? 0.f : im[b*128 + (i1-1)];
      lm = mye1 - mne1;
    } else lm = 0.f;
    float sl = mns * mne * (1.f - lm);
    int idx = b*SS + i;
    mk[idx]=mye; sel[idx]=sl; lastm[idx]=lm; endm[idx]=em; ep[idx]=mye;
  } else if (i == SS) { um[b] = 1.f; }
  else if (i == SS+1 && b==0) { flag[0] = 0; }
}

__global__ __launch_bounds__(256) void build_seq(
    const float* __restrict__ seqin, const float* __restrict__ START,
    const float* __restrict__ END, const float* __restrict__ mk,
    const float* __restrict__ endm, float* __restrict__ out){
  int r = blockIdx.x; int b = r/SS, i = r%SS; int t = threadIdx.x;
  float em = endm[r], m = mk[r];
  #pragma unroll
  for (int q=0;q<4;q++){
    int j = t + q*256;
    float v;
    if (i==0) v = START[j];
    else if (i<=128) v = seqin[((size_t)b*128 + (i-1))*DD + j];
    else v = 0.f;
    v = em*END[j] + (1.f-em)*v;
    out[(size_t)r*DD + j] = v*m;
  }
}

// ---- weight transpose+convert (PRE tiers): W[K][N] f32 -> WT hi/lo [N][K] f16 ----
__global__ __launch_bounds__(256) void wtranspose(
    const float* __restrict__ W, _Float16* __restrict__ WTh, _Float16* __restrict__ WTl,
    int K, int N){
  __shared__ float Ts[32][33];
  int k0 = blockIdx.x*32, n0 = blockIdx.y*32;
  int t = threadIdx.x;
  int r = t>>3, c4 = (t&7)*4;
  float4 v = *(const float4*)(W + (size_t)(k0+r)*N + n0 + c4);
  Ts[r][c4]=v.x; Ts[r][c4+1]=v.y; Ts[r][c4+2]=v.z; Ts[r][c4+3]=v.w;
  __syncthreads();
  int n = t>>3, k4 = (t&7)*4;
  f16x4 h, lo;
  #pragma unroll
  for (int i=0;i<4;i++){
    hl2 e = enc(Ts[k4+i][n] * 64.f);
    h[i] = e.h; lo[i] = e.l;
  }
  *(f16x4*)(WTh + (size_t)(n0+n)*K + k0+k4) = h;
  *(f16x4*)(WTl + (size_t)(n0+n)*K + k0+k4) = lo;
}

// ---- MFMA GEMM: C[M,N] = planes-A[M,K] @ W[K,N], 128x128 tile, 4 waves ----
// LDS linear [row][32] f16, 4 chunks/row; chunk slot q holds octet q^sw4(row).
// act: 0 f32 store, 1 gelu + planes store, 2 gelu + fused scorer partial
template<bool PREW>
__global__ __launch_bounds__(256,2) void gemm_mfma(
    GemmSrcP S, long lda,
    const _Float16* __restrict__ WTh, const _Float16* __restrict__ WTl,
    const float* __restrict__ Wf, int Nw,
    const float* __restrict__ bias,
    float* __restrict__ C, _Float16* __restrict__ Ch, _Float16* __restrict__ Cl,
    long ldc, int K, int act,
    const int* __restrict__ flag, float* __restrict__ spart, const float* __restrict__ Ws){
  if (flag[0]) return;
  __shared__ _Float16 Ah[128*32], Al[128*32];
  __shared__ _Float16 Wh[128*32], Wl[128*32];
  const int t = threadIdx.x;
  const int wave = t >> 6, lane = t & 63;
  const int wm = wave >> 1, wn = wave & 1;
  const int l15 = lane & 15, l4 = lane >> 4;
  // bijective XCD-chunked remap, m-fastest within chunk
  int lin = blockIdx.y * gridDim.x + blockIdx.x;
  int nwg = gridDim.x * gridDim.y;
  int q = nwg >> 3, r = nwg & 7;
  int xcd = lin & 7, pos = lin >> 3;
  int wg = (xcd < r) ? (xcd*(q+1) + pos) : (r*(q+1) + (xcd - r)*q + pos);
  int MT = gridDim.y;
  int mt = wg % MT, nt = wg / MT;
  const long mb = (long)mt * 128;
  const int  nb = nt * 128;
  f32x4 accH[4][4], accX[4][4];
  #pragma unroll
  for (int i=0;i<4;i++)
    #pragma unroll
    for (int j=0;j<4;j++){ accH[i][j] = (f32x4){0.f,0.f,0.f,0.f}; accX[i][j] = (f32x4){0.f,0.f,0.f,0.f}; }

  for (int kt=0; kt<K; kt+=32){
    // ---- A stage: global_load_lds, per-lane sw-swizzled source ----
    #pragma unroll
    for (int p=0;p<2;p++){
      int f = t + 256*p;
      int m = f >> 2;
      int qs = f & 3;
      int qd = qs ^ sw4(m);
      int kg = kt + qd*8;
      const _Float16* sh = S.h[kg >> 10];
      const _Float16* sl = S.l[kg >> 10];
      size_t goff = (size_t)(mb + m)*lda + (kg & 1023);
      int lbase = (wave*64 + 256*p)*8;
      gload16(sh + goff, &Ah[lbase]);
      gload16(sl + goff, &Al[lbase]);
    }
    if constexpr (PREW){
      // ---- W stage: global_load_lds from preconverted [N][K] planes ----
      #pragma unroll
      for (int p=0;p<2;p++){
        int f = t + 256*p;
        int n = f >> 2;
        int qs = f & 3;
        int qd = qs ^ sw4(n);
        size_t goff = (size_t)(nb + n)*K + kt + qd*8;
        int lbase = (wave*64 + 256*p)*8;
        gload16(WTh + goff, &Wh[lbase]);
        gload16(WTl + goff, &Wl[lbase]);
      }
    } else {
      // ---- W stage: coalesced reg-staged transpose+split from f32 W[K][N] ----
      // thread u: k-pair kp=u>>5 (rows kt+2kp, kt+2kp+1), col group c=u&31,
      // n = c+32*i. Loads lane-consecutive along n (coalesced).
      #pragma unroll
      for (int p=0;p<2;p++){
        int u = t + 256*p;
        int kp = u >> 5;
        int c  = u & 31;
        const float* wsrc = Wf + (size_t)(kt + 2*kp)*Nw + nb + c;
        #pragma unroll
        for (int i=0;i<4;i++){
          int n = c + 32*i;
          hl2 e0 = enc(wsrc[32*i] * 64.f);
          hl2 e1 = enc(wsrc[(size_t)Nw + 32*i] * 64.f);
          f16x2 hp; hp[0]=e0.h; hp[1]=e1.h;
          f16x2 lp; lp[0]=e0.l; lp[1]=e1.l;
          int slot = (kp>>2) ^ sw4(n);
          int off = n*32 + slot*8 + 2*(kp&3);
          *(f16x2*)&Wh[off] = hp;
          *(f16x2*)&Wl[off] = lp;
        }
      }
    }
    __syncthreads();
    f16x8 wh[4], wl[4];
    #pragma unroll
    for (int i=0;i<4;i++){
      int rw = wn*64 + i*16 + l15;
      int off = rw*32 + (l4 ^ sw4(rw))*8;
      wh[i] = *(const f16x8*)&Wh[off];
      wl[i] = *(const f16x8*)&Wl[off];
    }
    #pragma unroll
    for (int mi=0;mi<4;mi++){
      int ra = wm*64 + mi*16 + l15;
      int off = ra*32 + (l4 ^ sw4(ra))*8;
      f16x8 ahv = *(const f16x8*)&Ah[off];
      f16x8 alv = *(const f16x8*)&Al[off];
      #pragma unroll
      for (int ni=0;ni<4;ni++){
        accH[mi][ni] = __builtin_amdgcn_mfma_f32_16x16x32_f16(wh[ni], ahv, accH[mi][ni], 0,0,0);
        accX[mi][ni] = __builtin_amdgcn_mfma_f32_16x16x32_f16(wh[ni], alv, accX[mi][ni], 0,0,0);
        accX[mi][ni] = __builtin_amdgcn_mfma_f32_16x16x32_f16(wl[ni], ahv, accX[mi][ni], 0,0,0);
      }
    }
    __syncthreads();
  }

  const float IH = 1.f/64.f, IX = 1.f/131072.f;
  if (act==2){
    #pragma unroll
    for (int mi=0;mi<4;mi++){
      float s = 0.f;
      #pragma unroll
      for (int ni=0;ni<4;ni++){
        int nbase = nb + wn*64 + ni*16 + 4*l4;
        #pragma unroll
        for (int rr=0;rr<4;rr++){
          float v = gelu_(accH[mi][ni][rr]*IH + accX[mi][ni][rr]*IX + bias[nbase+rr]);
          s = fmaf(v, Ws[nbase+rr], s);
        }
      }
      s += __shfl_xor(s, 16);
      s += __shfl_xor(s, 32);
      if (l4==0){
        long m = mb + wm*64 + mi*16 + l15;
        spart[m*16 + nt*2 + wn] = s;
      }
    }
    return;
  }
  #pragma unroll
  for (int mi=0;mi<4;mi++){
    long m = mb + wm*64 + mi*16 + l15;
    #pragma unroll
    for (int ni=0;ni<4;ni++){
      int nbase = nb + wn*64 + ni*16 + 4*l4;
      float v0 = accH[mi][ni][0]*IH + accX[mi][ni][0]*IX + bias[nbase+0];
      float v1 = accH[mi][ni][1]*IH + accX[mi][ni][1]*IX + bias[nbase+1];
      float v2 = accH[mi][ni][2]*IH + accX[mi][ni][2]*IX + bias[nbase+2];
      float v3 = accH[mi][ni][3]*IH + accX[mi][ni][3]*IX + bias[nbase+3];
      if (act==1){
        v0=gelu_(v0); v1=gelu_(v1); v2=gelu_(v2); v3=gelu_(v3);
        hl2 e0=enc(v0), e1=enc(v1), e2=enc(v2), e3=enc(v3);
        f16x4 h4; h4[0]=e0.h; h4[1]=e1.h; h4[2]=e2.h; h4[3]=e3.h;
        f16x4 l4v; l4v[0]=e0.l; l4v[1]=e1.l; l4v[2]=e2.l; l4v[3]=e3.l;
        *(f16x4*)(Ch + m*ldc + nbase) = h4;
        *(f16x4*)(Cl + m*ldc + nbase) = l4v;
      } else {
        float4 v; v.x=v0; v.y=v1; v.z=v2; v.w=v3;
        *(float4*)(C + m*ldc + nbase) = v;
      }
    }
  }
}

// ---- f32 GEMM (init only) ----
__global__ __launch_bounds__(256,2) void gemm_f32(
    GemmSrcF S, long lda, const float* __restrict__ B, const float* __restrict__ bias,
    float* __restrict__ C, long ldc, int N, int K, int act,
    const int* __restrict__ flag){
  if (flag[0]) return;
  __shared__ float Asm[16][132];
  __shared__ float Bsm[16][132];
  float acc[8][8];
  #pragma unroll
  for (int i=0;i<8;i++)
    #pragma unroll
    for (int j=0;j<8;j++) acc[i][j]=0.f;
  const int t = threadIdx.x;
  const int tx = t & 15, ty = t >> 4;
  const long mb = (long)blockIdx.y * 128;
  const int  nb = blockIdx.x * 128;
  for (int kt=0; kt<K; kt+=16){
    #pragma unroll
    for (int ii=0; ii<2; ii++){
      int f  = t + 256*ii;
      int m  = f >> 2;
      int k4 = (f & 3) * 4;
      int kg = kt + k4;
      const float* src = S.a[kg >> 10];
      float4 v = *(const float4*)(src + (mb + m)*lda + (kg & 1023));
      Asm[k4+0][m]=v.x; Asm[k4+1][m]=v.y; Asm[k4+2][m]=v.z; Asm[k4+3][m]=v.w;
    }
    #pragma unroll
    for (int ii=0; ii<2; ii++){
      int f  = t + 256*ii;
      int kk = f >> 5;
      int c4 = (f & 31)*4;
      *(float4*)&Bsm[kk][c4] = *(const float4*)(B + (long)(kt+kk)*N + nb + c4);
    }
    __syncthreads();
    #pragma unroll
    for (int kk=0;kk<16;kk++){
      float av[8], bv[8];
      *(float4*)&av[0] = *(const float4*)&Asm[kk][ty*4];
      *(float4*)&av[4] = *(const float4*)&Asm[kk][64+ty*4];
      *(float4*)&bv[0] = *(const float4*)&Bsm[kk][tx*4];
      *(float4*)&bv[4] = *(const float4*)&Bsm[kk][64+tx*4];
      #pragma unroll
      for (int r=0;r<8;r++)
        #pragma unroll
        for (int c=0;c<8;c++) acc[r][c] = fmaf(av[r],bv[c],acc[r][c]);
    }
    __syncthreads();
  }
  #pragma unroll
  for (int rh=0;rh<2;rh++)
  #pragma unroll
  for (int rr=0;rr<4;rr++){
    long row = mb + rh*64 + ty*4 + rr;
    #pragma unroll
    for (int ch=0;ch<2;ch++){
      int col = nb + ch*64 + tx*4;
      float4 v;
      v.x = acc[rh*4+rr][ch*4+0] + bias[col+0];
      v.y = acc[rh*4+rr][ch*4+1] + bias[col+1];
      v.z = acc[rh*4+rr][ch*4+2] + bias[col+2];
      v.w = acc[rh*4+rr][ch*4+3] + bias[col+3];
      *(float4*)(C + row*ldc + col) = v;
    }
  }
}

// ---- batched neighbor GEMM: Y[b] = P[b](130x130,pad132) @ X[b](130x1024) ----
__global__ __launch_bounds__(256,2) void bgemm(
    const float* __restrict__ P,
    const _Float16* __restrict__ Xh, const _Float16* __restrict__ Xl,
    _Float16* __restrict__ Yh, _Float16* __restrict__ Yl,
    const int* __restrict__ flag){
  if (flag[0]) return;
  __shared__ float Ps[64][17];
  __shared__ float Xs[16][132];
  const int t = threadIdx.x;
  const int nt = blockIdx.x, mt = blockIdx.y, b = blockIdx.z;
  const int i0 = mt*64;
  const float* Pb = P + (size_t)b*SS*LSTR;
  const _Float16* Xhb = Xh + (size_t)b*SS*DD + nt*128;
  const _Float16* Xlb = Xl + (size_t)b*SS*DD + nt*128;
  _Float16* Yhb = Yh + (size_t)b*SS*DD + nt*128;
  _Float16* Ylb = Yl + (size_t)b*SS*DD + nt*128;
  const int tx = t & 7, ty = t >> 3;
  float acc[2][16];
  #pragma unroll
  for (int r=0;r<2;r++)
    #pragma unroll
    for (int c=0;c<16;c++) acc[r][c]=0.f;
  for (int j0=0;j0<SS;j0+=16){
    { int r = t>>2, c0 = (t&3)*4;
      float4 v = make_float4(0.f,0.f,0.f,0.f);
      if (i0 + r < SS && j0 + c0 < LSTR) v = *(const float4*)(Pb + (size_t)(i0+r)*LSTR + j0 + c0);
      Ps[r][c0]=v.x; Ps[r][c0+1]=v.y; Ps[r][c0+2]=v.z; Ps[r][c0+3]=v.w;
    }
    #pragma unroll
    for (int ii=0;ii<2;ii++){
      int f = t + 256*ii;
      int jj = f>>5, c4 = (f&31)*4;
      float x0=0.f,x1=0.f,x2=0.f,x3=0.f;
      if (j0 + jj < SS){
        f16x4 xh = *(const f16x4*)(Xhb + (size_t)(j0+jj)*DD + c4);
        f16x4 xl = *(const f16x4*)(Xlb + (size_t)(j0+jj)*DD + c4);
        x0 = (float)xh[0] + (float)xl[0]*IRS;
        x1 = (float)xh[1] + (float)xl[1]*IRS;
        x2 = (float)xh[2] + (float)xl[2]*IRS;
        x3 = (float)xh[3] + (float)xl[3]*IRS;
      }
      Xs[jj][c4]=x0; Xs[jj][c4+1]=x1; Xs[jj][c4+2]=x2; Xs[jj][c4+3]=x3;
    }
    __syncthreads();
    #pragma unroll
    for (int jj=0;jj<16;jj++){
      float p0 = Ps[2*ty][jj], p1 = Ps[2*ty+1][jj];
      #pragma unroll
      for (int q=0;q<4;q++){
        float4 xv = *(const float4*)&Xs[jj][tx*4 + 32*q];
        acc[0][q*4+0] = fmaf(p0,xv.x,acc[0][q*4+0]);
        acc[0][q*4+1] = fmaf(p0,xv.y,acc[0][q*4+1]);
        acc[0][q*4+2] = fmaf(p0,xv.z,acc[0][q*4+2]);
        acc[0][q*4+3] = fmaf(p0,xv.w,acc[0][q*4+3]);
        acc[1][q*4+0] = fmaf(p1,xv.x,acc[1][q*4+0]);
        acc[1][q*4+1] = fmaf(p1,xv.y,acc[1][q*4+1]);
        acc[1][q*4+2] = fmaf(p1,xv.z,acc[1][q*4+2]);
        acc[1][q*4+3] = fmaf(p1,xv.w,acc[1][q*4+3]);
      }
    }
    __syncthreads();
  }
  #pragma unroll
  for (int rr=0;rr<2;rr++){
    int row = i0 + 2*ty + rr;
    if (row < SS){
      #pragma unroll
      for (int q=0;q<4;q++){
        hl2 e0 = enc(acc[rr][q*4+0]);
        hl2 e1 = enc(acc[rr][q*4+1]);
        hl2 e2 = enc(acc[rr][q*4+2]);
        hl2 e3 = enc(acc[rr][q*4+3]);
        f16x4 h4; h4[0]=e0.h; h4[1]=e1.h; h4[2]=e2.h; h4[3]=e3.h;
        f16x4 l4v; l4v[0]=e0.l; l4v[1]=e1.l; l4v[2]=e2.l; l4v[3]=e3.l;
        *(f16x4*)(Yhb + (size_t)row*DD + tx*4 + 32*q) = h4;
        *(f16x4*)(Ylb + (size_t)row*DD + tx*4 + 32*q) = l4v;
      }
    }
  }
}

// ---------------- neighbor probabilities: wave-per-row prefix/suffix scan ----------------
__global__ __launch_bounds__(256) void neighbor_kernel(
    const float* __restrict__ ep, const float* __restrict__ mk,
    float* __restrict__ L, float* __restrict__ R, const int* __restrict__ flag){
  if (flag[0]) return;
  int wave = threadIdx.x >> 6, lane = threadIdx.x & 63;
  int idx = blockIdx.x*4 + wave;
  if (idx >= MM) return;
  int b = idx / SS, i = idx % SS;
  const float* p = ep + b*SS;
  const float* m = mk + b*SS;
  float mR[3], mL[3], mv[3];
  #pragma unroll
  for (int c=0;c<3;c++){
    int j = lane + 64*c;
    float pj = (j<SS)? p[j] : 0.f;
    float mj = (j<SS)? m[j] : 0.f;
    mv[c] = mj;
    float x = pj*mj;
    mR[c] = (j>i)? x : 0.f;
    mL[c] = (j<i)? x : 0.f;
  }
  float csR[3]; float run = 0.f;
  #pragma unroll
  for (int c=0;c<3;c++){
    float s = mR[c];
    #pragma unroll
    for (int o=1;o<64;o<<=1){ float v = __shfl_up(s,o); if (lane>=o) s += v; }
    csR[c] = s + run;
    run += __shfl(s,63);
  }
  float csL[3]; run = 0.f;
  #pragma unroll
  for (int cc=0;cc<3;cc++){
    int c = 2-cc;
    float s = mL[c];
    #pragma unroll
    for (int o=1;o<64;o<<=1){ float v = __shfl_down(s,o); if (lane < 64-o) s += v; }
    csL[c] = s + run;
    run += __shfl(s,0);
  }
  float* Lr = L + (size_t)idx*LSTR;
  float* Rr = R + (size_t)idx*LSTR;
  #pragma unroll
  for (int c=0;c<3;c++){
    int j = lane + 64*c;
    if (j < LSTR){
      float rv = 0.f, lv = 0.f;
      if (j < SS){
        rv = ((csR[c]>1.f) ? fmaxf(1.f-(csR[c]-mR[c]),0.f) : mR[c]) * mv[c];
        lv = ((csL[c]>1.f) ? fmaxf(1.f-(csL[c]-mL[c]),0.f) : mL[c]) * mv[c];
      }
      Rr[j] = rv; Lr[j] = lv;
    }
  }
}

// ---------------- LN after init: f32 in -> sq planes out ----------------
__global__ __launch_bounds__(256) void ln1_kernel(
    const float* __restrict__ xin, const float* __restrict__ g, const float* __restrict__ bb,
    const float* __restrict__ mk, _Float16* __restrict__ sqh, _Float16* __restrict__ sql){
  int r = blockIdx.x, t = threadIdx.x;
  const float* xr = xin + (size_t)r*DD;
  float x[4]; float s=0.f;
  #pragma unroll
  for (int q=0;q<4;q++){ x[q]=xr[t+256*q]; s+=x[q]; }
  float mean = bsum(s)*(1.f/DD);
  float vs=0.f;
  #pragma unroll
  for (int q=0;q<4;q++){ float d=x[q]-mean; vs+=d*d; }
  float var = bsum(vs)*(1.f/DD);
  float inv = 1.f/sqrtf(var+1e-5f);
  float m = mk[r];
  #pragma unroll
  for (int q=0;q<4;q++){
    int j=t+256*q;
    float v = ((x[q]-mean)*inv*g[j]+bb[j])*m;
    hl2 e = enc(v);
    sqh[(size_t)r*DD+j] = e.h; sql[(size_t)r*DD+j] = e.l;
  }
}

// ---------------- scorer finalize / max / tp ----------------
__global__ void scorer_final(const float* __restrict__ spart, const float* __restrict__ bs,
                             float* __restrict__ sc, const int* __restrict__ flag){
  if (flag[0]) return;
  int r = blockIdx.x*blockDim.x + threadIdx.x;
  if (r >= MM) return;
  float s = bs[0];
  #pragma unroll
  for (int k=0;k<16;k++) s += spart[(size_t)r*16+k];
  sc[r] = s;
}
__global__ __launch_bounds__(256) void max1(const float* __restrict__ sc, float* __restrict__ part,
                                            const int* __restrict__ flag){
  if (flag[0]) return;
  int idx = blockIdx.x*256 + threadIdx.x;
  float v = -1e30f;
  for (int i = idx; i < MM; i += 64*256) v = fmaxf(v, sc[i]);
  v = bmaxr(v);
  if (threadIdx.x==0) part[blockIdx.x] = v;
}
__global__ __launch_bounds__(64) void max2(const float* __restrict__ part, float* __restrict__ gm,
                                           const int* __restrict__ flag){
  if (flag[0]) return;
  float v = part[threadIdx.x];
  #pragma unroll
  for (int o=32;o;o>>=1) v = fmaxf(v, __shfl_down(v,o));
  if (threadIdx.x==0) gm[0] = fmaxf(v, 0.f);
}
__global__ void tp_kernel(const float* __restrict__ sc, const float* __restrict__ sel,
                          const float* __restrict__ um, const float* __restrict__ gm,
                          float* __restrict__ tp, const int* __restrict__ flag){
  if (flag[0]) return;
  int idx = blockIdx.x*blockDim.x + threadIdx.x;
  if (idx>=MM) return;
  int b = idx / SS;
  float g = gm[0];
  float et = expf(sc[idx]-g)*sel[idx];
  float en = expf(-g);
  tp[idx] = et/(et+en+2e-8f)*um[b];
}

// ---- gates + LN + blend, planes in/out, row-chunked ----
__global__ __launch_bounds__(256) void update_kernel(
    const float* __restrict__ cont,
    const _Float16* __restrict__ l1h, const _Float16* __restrict__ l1l,
    _Float16* __restrict__ sqh, _Float16* __restrict__ sql,
    const float* __restrict__ tp, const float* __restrict__ g, const float* __restrict__ bb,
    const int* __restrict__ flag, long row0){
  if (flag[0]) return;
  long r = row0 + blockIdx.x; int t = threadIdx.x;
  const float* cr = cont + (size_t)blockIdx.x*4096;
  const _Float16* lh = l1h + (size_t)r*DD;
  const _Float16* ll = l1l + (size_t)r*DD;
  _Float16* sh = sqh + (size_t)r*DD;
  _Float16* sl = sql + (size_t)r*DD;
  float x[4], sv[4];
  float s=0.f;
  #pragma unroll
  for (int q=0;q<4;q++){
    int j = t+q*256;
    float c0=cr[j], c1=cr[DD+j], c2=cr[2*DD+j], c3=cr[3*DD+j];
    float g0=1.f/(1.f+expf(-c0));
    float g1=1.f/(1.f+expf(-c1));
    float g2=1.f/(1.f+expf(-c2));
    float lv = (float)lh[j] + (float)ll[j]*IRS;
    float sqv = (float)sh[j] + (float)sl[j]*IRS;
    sv[q]=sqv;
    x[q] = g0*lv + g1*sqv + g2*c3;
    s += x[q];
  }
  float mean = bsum(s)*(1.f/DD);
  float vs=0.f;
  #pragma unroll
  for (int q=0;q<4;q++){ float d=x[q]-mean; vs+=d*d; }
  float var = bsum(vs)*(1.f/DD);
  float inv = 1.f/sqrtf(var+1e-5f);
  float tpv = tp[r];
  #pragma unroll
  for (int q=0;q<4;q++){
    int j=t+q*256;
    float comp = (x[q]-mean)*inv*g[j]+bb[j];
    float out = tpv*comp + (1.f-tpv)*sv[q];
    hl2 e = enc(out);
    sh[j]=e.h; sl[j]=e.l;
  }
}

// ---------------- ep update: wave-per-row dot ----------------
__global__ __launch_bounds__(256) void ep_update(
    float* __restrict__ ep, const float* __restrict__ R,
    const float* __restrict__ tp, const int* __restrict__ flag){
  if (flag[0]) return;
  int wave = threadIdx.x >> 6, lane = threadIdx.x & 63;
  int idx = blockIdx.x*4 + wave;
  if (idx >= MM) return;
  int b = idx / SS;
  const float* Rr = R + (size_t)idx*LSTR;
  const float* tb = tp + b*SS;
  float d = 0.f;
  #pragma unroll
  for (int c=0;c<3;c++){
    int j = lane + 64*c;
    if (j < SS) d = fmaf(Rr[j], tb[j], d);
  }
  #pragma unroll
  for (int o=32;o;o>>=1) d += __shfl_xor(d,o);
  if (lane==0) ep[idx] *= (1.f - d);
}

__global__ __launch_bounds__(256) void active_um(const float* __restrict__ ep,
                                                 const float* __restrict__ sel,
                                                 float* __restrict__ um,
                                                 const int* __restrict__ flag){
  if (flag[0]) return;
  int b = blockIdx.x, t = threadIdx.x;
  float s = (t<SS) ? ep[b*SS+t]*sel[b*SS+t] : 0.f;
  s = bsum(s);
  if (t==0) um[b] *= (s >= 0.1f) ? 1.f : 0.f;
}
__global__ __launch_bounds__(64) void done_kernel(const float* __restrict__ um, int* __restrict__ flag){
  float v = um[threadIdx.x];
  unsigned long long b = __ballot(v > 0.f);
  if (threadIdx.x==0) flag[0] = (b==0ULL) ? 1 : 0;
}

// ---------------- outputs (reconstruct sq from planes) ----------------
__global__ __launch_bounds__(256) void output_kernel(
    const _Float16* __restrict__ sqh, const _Float16* __restrict__ sql,
    const float* __restrict__ mk, float* __restrict__ out){
  int r = blockIdx.x; int b = r/SS, i = r%SS;
  if (i<1 || i>128) return;
  float m = mk[r]; int t=threadIdx.x;
  #pragma unroll
  for (int q=0;q<4;q++){
    int j = t+q*256;
    float v = (float)sqh[(size_t)r*DD+j] + (float)sql[(size_t)r*DD+j]*IRS;
    out[((size_t)b*128 + (i-1))*DD + j] = v*m;
  }
}
__global__ __launch_bounds__(256) void gstate_kernel(
    const _Float16* __restrict__ sqh, const _Float16* __restrict__ sql,
    const float* __restrict__ mk, const float* __restrict__ lastm,
    float* __restrict__ outg){
  int b = blockIdx.x; int t=threadIdx.x;
  #pragma unroll
  for (int q=0;q<4;q++){
    int j = t+q*256;
    float acc=0.f;
    for (int i=0;i<SS;i++){
      float w = lastm[b*SS+i]*mk[b*SS+i];
      size_t o = ((size_t)(b*SS+i))*DD + j;
      float v = (float)sqh[o] + (float)sql[o]*IRS;
      acc = fmaf(w, v, acc);
    }
    outg[(size_t)b*DD + j] = acc;
  }
}

extern "C" void kernel_launch(void* const* d_in, const int* in_sizes, int n_in,
                              void* d_out, int out_size, void* d_ws, size_t ws_size,
                              hipStream_t stream) {
  const float* sequence   = (const float*)d_in[0];
  const float* input_mask = (const float*)d_in[1];
  const float* START      = (const float*)d_in[2];
  const float* END        = (const float*)d_in[3];
  const float* W_conv     = (const float*)d_in[4];
  const float* b_conv     = (const float*)d_in[5];
  const float* W_scorer   = (const float*)d_in[6];
  const float* b_scorer   = (const float*)d_in[7];
  const float* W_init     = (const float*)d_in[8];
  const float* b_init     = (const float*)d_in[9];
  const float* W_cell1    = (const float*)d_in[10];
  const float* b_cell1    = (const float*)d_in[11];
  const float* W_cell2    = (const float*)d_in[12];
  const float* b_cell2    = (const float*)d_in[13];
  const float* ln1g       = (const float*)d_in[14];
  const float* ln1b       = (const float*)d_in[15];
  const float* ln2g       = (const float*)d_in[16];
  const float* ln2b       = (const float*)d_in[17];

  float* ws = (float*)d_ws;
  const size_t U = (size_t)MM*DD;
  _Float16* sq_h = (_Float16*)(ws);        _Float16* sq_l = sq_h + U;
  _Float16* l1_h = (_Float16*)(ws + U);    _Float16* l1_l = l1_h + U;
  _Float16* r1_h = (_Float16*)(ws + 2*U);  _Float16* r1_l = r1_h + U;
  _Float16* l2_h = (_Float16*)(ws + 3*U);  _Float16* l2_l = l2_h + U;  // also hid planes (chunk)
  _Float16* r2_h = (_Float16*)(ws + 4*U);  _Float16* r2_l = r2_h + U;
  float* contb = ws + 4*U;                 // cont f32 chunk aliases r2 region
  float* seqtmp  = ws + U;                 // init scratch (l1 region as f32)
  float* inittmp = ws + 2*U;               // init scratch (r1 region as f32)
  float* Lm   = ws + 5*U;
  float* Rm   = Lm + (size_t)NB*SS*LSTR;
  float* maskv= Rm + (size_t)NB*SS*LSTR;
  float* sel  = maskv + MM;
  float* lastm= sel + MM;
  float* endm = lastm + MM;
  float* ep   = endm + MM;
  float* scb  = ep + MM;
  float* tpb  = scb + MM;
  float* spart= tpb + MM;          // MM*16
  float* umb  = spart + (size_t)MM*16;
  float* part = umb + NB;
  float* gmx  = part + 64;
  int*   flag = (int*)(gmx + 4);
  size_t used_floats = (size_t)((float*)(flag+4) - ws);
  used_floats = (used_floats + 7) & ~(size_t)7;
  const size_t SC = (size_t)1024*5120, S1 = (size_t)4096*2048, S2 = (size_t)4096*4096;
  _Float16* WT2_h = (_Float16*)(ws + used_floats);
  _Float16* WT2_l = WT2_h + S2;
  _Float16* WT1_h = WT2_l + S2;
  _Float16* WT1_l = WT1_h + S1;
  _Float16* WTc_h = WT1_l + S1;
  _Float16* WTc_l = WTc_h + SC;
  const bool pre2 = ws_size >= (size_t)((char*)(WT2_l + S2) - (char*)d_ws);
  const bool pre1 = ws_size >= (size_t)((char*)(WT1_l + S1) - (char*)d_ws);
  const bool prec = ws_size >= (size_t)((char*)(WTc_l + SC) - (char*)d_ws);

  build_masks<<<NB,256,0,stream>>>(input_mask, maskv, sel, lastm, endm, ep, umb, flag);
  build_seq<<<MM,256,0,stream>>>(sequence, START, END, maskv, endm, seqtmp);
  GemmSrcF si; si.a[0]=seqtmp; si.a[1]=seqtmp; si.a[2]=seqtmp; si.a[3]=seqtmp; si.a[4]=seqtmp;
  gemm_f32<<<dim3(8,65),256,0,stream>>>(si, DD, W_init, b_init, inittmp, DD, DD, DD, 0, flag);
  ln1_kernel<<<MM,256,0,stream>>>(inittmp, ln1g, ln1b, maskv, sq_h, sq_l);

  if (pre2) wtranspose<<<dim3(128,128),256,0,stream>>>(W_cell2, WT2_h, WT2_l, 4096, 4096);
  if (pre1) wtranspose<<<dim3(64,128),256,0,stream>>>(W_cell1, WT1_h, WT1_l, 2048, 4096);
  if (prec) wtranspose<<<dim3(160,32),256,0,stream>>>(W_conv,  WTc_h, WTc_l, 5120, 1024);

  const int NBLK = (MM + 3) / 4;
  for (int it=0; it<25; ++it){
    neighbor_kernel<<<NBLK,256,0,stream>>>(ep, maskv, Lm, Rm, flag);
    bgemm<<<dim3(8,3,NB),256,0,stream>>>(Lm, sq_h, sq_l, l1_h, l1_l, flag);
    bgemm<<<dim3(8,3,NB),256,0,stream>>>(Rm, sq_h, sq_l, r1_h, r1_l, flag);
    bgemm<<<dim3(8,3,NB),256,0,stream>>>(Lm, l1_h, l1_l, l2_h, l2_l, flag);
    bgemm<<<dim3(8,3,NB),256,0,stream>>>(Rm, r1_h, r1_l, r2_h, r2_l, flag);
    GemmSrcP s5;
    s5.h[0]=l2_h; s5.h[1]=l1_h; s5.h[2]=sq_h; s5.h[3]=r1_h; s5.h[4]=r2_h;
    s5.l[0]=l2_l; s5.l[1]=l1_l; s5.l[2]=sq_l; s5.l[3]=r1_l; s5.l[4]=r2_l;
    if (prec)
      gemm_mfma<true ><<<dim3(8,65),256,0,stream>>>(s5, DD, WTc_h, WTc_l, nullptr, 0, b_conv, nullptr, nullptr, nullptr, 0, 5120, 2, flag, spart, W_scorer);
    else
      gemm_mfma<false><<<dim3(8,65),256,0,stream>>>(s5, DD, nullptr, nullptr, W_conv, 1024, b_conv, nullptr, nullptr, nullptr, 0, 5120, 2, flag, spart, W_scorer);
    scorer_final<<<(MM+255)/256,256,0,stream>>>(spart, b_scorer, scb, flag);
    max1<<<64,256,0,stream>>>(scb, part, flag);
    max2<<<1,64,0,stream>>>(part, gmx, flag);
    tp_kernel<<<(MM+255)/256,256,0,stream>>>(scb, sel, umb, gmx, tpb, flag);
    for (int c=0;c<5;c++){
      long row0 = (long)c*CROWS;
      GemmSrcP s2;
      s2.h[0]=l1_h+row0*DD; s2.h[1]=sq_h+row0*DD; s2.h[2]=s2.h[1]; s2.h[3]=s2.h[1]; s2.h[4]=s2.h[1];
      s2.l[0]=l1_l+row0*DD; s2.l[1]=sq_l+row0*DD; s2.l[2]=s2.l[1]; s2.l[3]=s2.l[1]; s2.l[4]=s2.l[1];
      GemmSrcP s3;
      s3.h[0]=l2_h; s3.h[1]=l2_h+DD; s3.h[2]=l2_h+2*DD; s3.h[3]=l2_h+3*DD; s3.h[4]=l2_h;
      s3.l[0]=l2_l; s3.l[1]=l2_l+DD; s3.l[2]=l2_l+2*DD; s3.l[3]=l2_l+3*DD; s3.l[4]=l2_l;
      if (pre1)
        gemm_mfma<true ><<<dim3(32,13),256,0,stream>>>(s2, DD,   WT1_h, WT1_l, nullptr, 0, b_cell1, nullptr, l2_h, l2_l, 4096, 2048, 1, flag, nullptr, nullptr);
      else
        gemm_mfma<false><<<dim3(32,13),256,0,stream>>>(s2, DD,   nullptr, nullptr, W_cell1, 4096, b_cell1, nullptr, l2_h, l2_l, 4096, 2048, 1, flag, nullptr, nullptr);
      if (pre2)
        gemm_mfma<true ><<<dim3(32,13),256,0,stream>>>(s3, 4096, WT2_h, WT2_l, nullptr, 0, b_cell2, contb, nullptr, nullptr, 4096, 4096, 0, flag, nullptr, nullptr);
      else
        gemm_mfma<false><<<dim3(32,13),256,0,stream>>>(s3, 4096, nullptr, nullptr, W_cell2, 4096, b_cell2, contb, nullptr, nullptr, 4096, 4096, 0, flag, nullptr, nullptr);
      update_kernel<<<CROWS,256,0,stream>>>(contb, l1_h, l1_l, sq_h, sq_l, tpb, ln2g, ln2b, flag, row0);
    }
    ep_update<<<NBLK,256,0,stream>>>(ep, Rm, tpb, flag);
    active_um<<<NB,256,0,stream>>>(ep, sel, umb, flag);
    done_kernel<<<1,64,0,stream>>>(umb, flag);
  }

  float* out = (float*)d_out;
  output_kernel<<<MM,256,0,stream>>>(sq_h, sq_l, maskv, out);
  gstate_kernel<<<NB,256,0,stream>>>(sq_h, sq_l, maskv, lastm, out + (size_t)NB*128*DD);
}